// Round 10
// baseline (145.732 us; speedup 1.0000x reference)
//
#include <hip/hip_runtime.h>
#include <cmath>
#include <cstdint>

#define NW       14
#define NST      (1 << NW)      // 16384 amplitudes
#define THREADS  512
#define PRETHR   768
#define NPASS    12             // layers 1..3 x 4 groups
#define WTP      512            // per-pass W table: TR[256] + TI[256] f16

typedef _Float16 f16;
typedef _Float16 f16x8 __attribute__((ext_vector_type(8)));
typedef float    f32x4 __attribute__((ext_vector_type(4)));
typedef unsigned short u16;

// Per-pass XOR-mask addressing with DECOUPLED read/write label frames:
// pass p reads in boundary-p frame (masks Mm/Mt/Mw = psi_p(phi-masks)),
// writes in boundary-(p+1) frame (masks Nm/Nt/Nw = psi_{p+1}(same)).
// Each psi is a bank-normalizing involution chosen host-side so that the
// lane->bits[5:4] map has rank 2 for reads AND writes of every pass.
struct PassArg { u16 Mm[4]; u16 Mt[3]; u16 Mw[3]; u16 Nm[4]; u16 Nt[3]; u16 Nw[3]; };
struct Plan { PassArg ps[NPASS]; u16 initM[14]; u16 measR; u16 _pad; };

__device__ __forceinline__ float2 cmulf(float2 a, float2 b) {
    return make_float2(a.x * b.x - a.y * b.y, a.x * b.y + a.y * b.x);
}
// W-table in-block offset with quad-spread (keeps 8-f16 alignment)
__device__ __host__ __forceinline__ unsigned wtofs(unsigned m, unsigned q01) {
    return (m * 16 + q01 * 8) ^ (((m >> 2) & 1u) << 3);
}

// ---------------- pre-kernel: shared tables (angles only) -> d_ws ----------------
__global__ __launch_bounds__(PRETHR)
void vqc_pre(const float* __restrict__ angles, f16* __restrict__ wt_g,
             float2* __restrict__ u0_g)
{
    __shared__ float2 G[4 * NW * 4];
    const int tid = threadIdx.x;

    if (tid < 4 * NW) {
        const int k = tid / NW, w = tid % NW;
        const float a  = angles[(k * NW + w) * 3 + 0];
        const float bb = angles[(k * NW + w) * 3 + 1];
        const float c  = angles[(k * NW + w) * 3 + 2];
        float sa, ca, sb, cb, sc, cc;
        sincosf(a * 0.5f, &sa, &ca);
        sincosf(bb * 0.5f, &sb, &cb);
        sincosf(c * 0.5f, &sc, &cc);
        float2 m00 = make_float2(cb * ca,  sb * sa);
        float2 m01 = make_float2(-sb * ca, -cb * sa);
        float2 m10 = make_float2(sb * ca,  -cb * sa);
        float2 m11 = make_float2(cb * ca,  -sb * sa);
        const float2 e0 = make_float2(cc, -sc), e1 = make_float2(cc, sc);
        const float2 u00 = cmulf(e0, m00), u01 = cmulf(e0, m01);
        const float2 u10 = cmulf(e1, m10), u11 = cmulf(e1, m11);
        const int gi = (k * NW + w) * 4;
        G[gi + 0] = u00; G[gi + 1] = u01; G[gi + 2] = u10; G[gi + 3] = u11;
        if (k == 0) {   // layer-0 STATIC gate (per-sample RY_enc folded in main kernel)
            u0_g[w * 4 + 0] = u00; u0_g[w * 4 + 1] = u01;
            u0_g[w * 4 + 2] = u10; u0_g[w * 4 + 3] = u11;
        }
    }
    __syncthreads();

    // W tables: TR[a'][a] = Re W[a'][a], TI = Im (16x16 per pass), layers 1..3
    {
        const int p = tid >> 6, l6 = tid & 63;
        const int ap = l6 & 15, ahalf = (l6 >> 4) & 1, dup = l6 >> 5;
        const int layer = (p >> 2) + 1, g = p & 3;

        float2 p3;
        if (g == 3) {
            p3 = make_float2((((ap >> 3) & 1) == ahalf) ? 1.f : 0.f, 0.f);
        } else {
            const int wire = 13 - (10 - 4 * g + 3);
            p3 = G[(layer * NW + wire) * 4 + ((ap >> 3) & 1) * 2 + ahalf];
        }
        float2 e0a, e0b, e1a, e1b, e2a, e2b;
        {
            const int r0 = ap & 1, r1 = (ap >> 1) & 1, r2 = (ap >> 2) & 1;
            if (g == 3) {
                const float2* G13 = G + (layer * NW + 13) * 4;
                const float2* G12 = G + (layer * NW + 12) * 4;
                e0a = G13[r0 * 2 + 0]; e0b = G13[r0 * 2 + 1];
                e1a = G12[r1 * 2 + 0]; e1b = G12[r1 * 2 + 1];
                e2a = make_float2(r2 == 0 ? 1.f : 0.f, 0.f);
                e2b = make_float2(r2 == 1 ? 1.f : 0.f, 0.f);
            } else {
                const float2* G0 = G + (layer * NW + (13 - (10 - 4 * g + 0))) * 4;
                const float2* G1 = G + (layer * NW + (13 - (10 - 4 * g + 1))) * 4;
                const float2* G2 = G + (layer * NW + (13 - (10 - 4 * g + 2))) * 4;
                e0a = G0[r0 * 2 + 0]; e0b = G0[r0 * 2 + 1];
                e1a = G1[r1 * 2 + 0]; e1b = G1[r1 * 2 + 1];
                e2a = G2[r2 * 2 + 0]; e2b = G2[r2 * 2 + 1];
            }
        }
        f16x8 frag;
        #pragma unroll
        for (int j2 = 0; j2 < 8; ++j2) {
            float2 v = cmulf(p3, (j2 & 4) ? e2b : e2a);
            v = cmulf(v, (j2 & 2) ? e1b : e1a);
            v = cmulf(v, (j2 & 1) ? e0b : e0a);
            frag[j2] = (f16)(dup ? v.y : v.x);
        }
        *(f16x8*)(wt_g + p * WTP + dup * 256 + wtofs(ap, ahalf)) = frag;
    }
}

// ---------------- main kernel: per-sample ----------------
__global__ __launch_bounds__(THREADS, 4)
void vqc_kernel(const float* __restrict__ x_raw, const f16* __restrict__ wt_g,
                const float2* __restrict__ u0_g, float* __restrict__ out, Plan pl)
{
    extern __shared__ char smem[];
    f16*    Sh  = (f16*)smem;                    // Re [0,16K), Im [16K,32K) f16 (64 KB)
    f16*    Wt  = Sh + 2 * NST;                  // 12 KB shared W tables
    float2* G0c = (float2*)(Wt + NPASS * WTP);   // 14 x {col0_row0, col0_row1}
    float*  red = (float*)(G0c + 2 * NW);

    const int b   = blockIdx.x;
    const int tid = threadIdx.x;
    const int lane = tid & 63, wv = tid >> 6;
    const int q = lane >> 4, m = lane & 15;

    // ---- stage shared W tables: global -> LDS (768 x 16 B, coalesced) ----
    {
        const uint4* src = (const uint4*)wt_g;
        uint4* dst = (uint4*)Wt;
        dst[tid] = src[tid];
        if (tid < 256) dst[512 + tid] = src[512 + tid];
    }
    // ---- per-sample layer-0 encode: col0 of U_static * RY_enc(x_w) ----
    if (tid < NW) {
        const float xe = tanhf(x_raw[b * NW + tid]) * 3.14159265358979f;
        float se, ce;
        sincosf(xe * 0.5f, &se, &ce);
        const float2 u00 = u0_g[tid * 4 + 0], u01 = u0_g[tid * 4 + 1];
        const float2 u10 = u0_g[tid * 4 + 2], u11 = u0_g[tid * 4 + 3];
        G0c[tid * 2 + 0] = make_float2(u00.x * ce + u01.x * se, u00.y * ce + u01.y * se);
        G0c[tid * 2 + 1] = make_float2(u10.x * ce + u11.x * se, u10.y * ce + u11.y * se);
    }
    __syncthreads();

    // ---- init: product state after all layer-0 1q gates, placed via initM ----
    {
        float2 common = make_float2(1.f, 0.f);
        #pragma unroll
        for (int bit = 0; bit < 9; ++bit) {          // x bits 0..8 from tid (wires 13..5)
            const int w = 13 - bit;
            const float2 f = ((tid >> bit) & 1) ? G0c[w * 2 + 1] : G0c[w * 2 + 0];
            common = cmulf(common, f);
        }
        unsigned p9 = 0;
        #pragma unroll
        for (int bit = 0; bit < 9; ++bit)
            p9 ^= ((tid >> bit) & 1) ? (unsigned)pl.initM[bit] : 0u;
        float2 f0[2], f1[2], f2[2], f3[2], f4[2];    // j bits 0..4 -> wires 4,3,2,1,0
        f0[0] = G0c[4*2+0]; f0[1] = G0c[4*2+1];
        f1[0] = G0c[3*2+0]; f1[1] = G0c[3*2+1];
        f2[0] = G0c[2*2+0]; f2[1] = G0c[2*2+1];
        f3[0] = G0c[1*2+0]; f3[1] = G0c[1*2+1];
        f4[0] = G0c[0*2+0]; f4[1] = G0c[0*2+1];
        #pragma unroll
        for (int j = 0; j < 32; ++j) {
            float2 o = cmulf(cmulf(f0[j & 1], f1[(j >> 1) & 1]),
                             cmulf(f2[(j >> 2) & 1], f3[(j >> 3) & 1]));
            o = cmulf(o, f4[(j >> 4) & 1]);
            const float2 amp = cmulf(common, o);
            const unsigned ph = p9
                ^ ((j & 1) ? pl.initM[9]  : 0) ^ ((j & 2)  ? pl.initM[10] : 0)
                ^ ((j & 4) ? pl.initM[11] : 0) ^ ((j & 8)  ? pl.initM[12] : 0)
                ^ ((j & 16) ? pl.initM[13] : 0);
            Sh[ph]       = (f16)amp.x;
            Sh[ph + NST] = (f16)amp.y;
        }
    }
    __syncthreads();

    // ---- 12 MFMA passes, in-place: read 8 tiles -> barrier -> MFMA+write -> barrier ----
    const unsigned plane_off = (unsigned)(q >> 1) << 14;
    const unsigned q01 = (unsigned)(q & 1);
    const f32x4 z4 = {0.f, 0.f, 0.f, 0.f};
    #pragma unroll
    for (int p = 0; p < NPASS; ++p) {
        const PassArg& P = pl.ps[p];
        const unsigned b0R = ((m & 1) ? P.Mm[0] : 0) ^ ((m & 2) ? P.Mm[1] : 0)
                           ^ ((m & 4) ? P.Mm[2] : 0) ^ ((m & 8) ? P.Mm[3] : 0)
                           ^ ((wv & 1) ? P.Mw[0] : 0) ^ ((wv & 2) ? P.Mw[1] : 0)
                           ^ ((wv & 4) ? P.Mw[2] : 0);
        const unsigned b0W = ((m & 1) ? P.Nm[0] : 0) ^ ((m & 2) ? P.Nm[1] : 0)
                           ^ ((m & 4) ? P.Nm[2] : 0) ^ ((m & 8) ? P.Nm[3] : 0)
                           ^ ((wv & 1) ? P.Nw[0] : 0) ^ ((wv & 2) ? P.Nw[1] : 0)
                           ^ ((wv & 4) ? P.Nw[2] : 0);
        const f16x8 tr = *(const f16x8*)(Wt + p * WTP +       wtofs((unsigned)m, q01));
        const f16x8 ti = *(const f16x8*)(Wt + p * WTP + 256 + wtofs((unsigned)m, q01));
        const f16x8 bf1 = (q < 2) ? tr : -ti;   // [Wr' ; -Wi']
        const f16x8 bf2 = (q < 2) ? ti : tr;    // [Wi' ;  Wr']
        f16x8 av[8];
        #pragma unroll
        for (int tt = 0; tt < 8; ++tt) {
            const unsigned swR = b0R ^ ((tt & 1) ? P.Mt[0] : 0)
                                     ^ ((tt & 2) ? P.Mt[1] : 0)
                                     ^ ((tt & 4) ? P.Mt[2] : 0);
            av[tt] = *(const f16x8*)(Sh + plane_off + (swR ^ (q01 << 3)));
        }
        __syncthreads();    // all reads complete before any in-place write
        #pragma unroll
        for (int tt = 0; tt < 8; ++tt) {
            const f32x4 d1 = __builtin_amdgcn_mfma_f32_16x16x32_f16(av[tt], bf1, z4, 0, 0, 0);
            const f32x4 d2 = __builtin_amdgcn_mfma_f32_16x16x32_f16(av[tt], bf2, z4, 0, 0, 0);
            union { f16 h[4]; uint2 u; } c1, c2;
            #pragma unroll
            for (int r = 0; r < 4; ++r) { c1.h[r] = (f16)d1[r]; c2.h[r] = (f16)d2[r]; }
            const unsigned wu = (b0W ^ ((tt & 1) ? P.Nt[0] : 0)
                                     ^ ((tt & 2) ? P.Nt[1] : 0)
                                     ^ ((tt & 4) ? P.Nt[2] : 0)) ^ ((unsigned)q << 2);
            *(uint2*)(Sh + wu)       = c1.u;   // Re plane, b64
            *(uint2*)(Sh + NST + wu) = c2.u;   // Im plane, b64
        }
        __syncthreads();
    }

    // ---- <Z_0>: sign = parity(s & measR); lane-interleaved chunks for bank spread ----
    float acc = 0.f;
    {
        const unsigned base = (unsigned)tid * 32;
        const int pb = __popc(base & (unsigned)pl.measR) & 1;
        #pragma unroll
        for (int cch = 0; cch < 4; ++cch) {
            const unsigned co = ((unsigned)cch ^ ((unsigned)(lane >> 1) & 3u)) * 8;
            const f16x8 rr = *(const f16x8*)(Sh + (base ^ co));
            const f16x8 ii = *(const f16x8*)(Sh + NST + (base ^ co));
            #pragma unroll
            for (int e = 0; e < 8; ++e) {
                const float re = (float)rr[e], im = (float)ii[e];
                const float pw = fmaf(re, re, im * im);
                const int sgn = pb ^ (__popc((co | (unsigned)e) & (unsigned)pl.measR) & 1);
                acc += sgn ? -pw : pw;
            }
        }
    }
    #pragma unroll
    for (int off = 32; off > 0; off >>= 1) acc += __shfl_down(acc, off);
    if ((tid & 63) == 0) red[wv] = acc;
    __syncthreads();
    if (tid == 0) {
        float s = 0.f;
        #pragma unroll
        for (int i = 0; i < THREADS / 64; ++i) s += red[i];
        out[b] = s;
    }
}

// ---------------- host-side GF(2) layout scheduling ----------------
struct GFm { u16 col[14]; };   // col[b] = image of e_b

static unsigned ringp_host(unsigned x) {
    unsigned s = x;
    s ^= s >> 1; s ^= s >> 2; s ^= s >> 4; s ^= s >> 8;
    s &= 0x3FFFu;
    return (s ^ ((s & 1u) << 13)) & 0x3FFFu;
}
static u16 gf_apply(const GFm& m, u16 v) {
    u16 r = 0;
    for (int b = 0; b < 14; ++b) if ((v >> b) & 1) r ^= m.col[b];
    return r;
}
static GFm gf_compose(const GFm& A, const GFm& B) {
    GFm C;
    for (int b = 0; b < 14; ++b) C.col[b] = gf_apply(A, B.col[b]);
    return C;
}
static void rows_from(const GFm& A, u16 r[14]) {
    for (int i = 0; i < 14; ++i) {
        u16 mm = 0;
        for (int b = 0; b < 14; ++b) mm |= (u16)(((A.col[b] >> i) & 1) << b);
        r[i] = mm;
    }
}
static GFm from_rows(const u16 r[14]) {
    GFm A;
    for (int b = 0; b < 14; ++b) {
        u16 c = 0;
        for (int i = 0; i < 14; ++i) c |= (u16)(((r[i] >> b) & 1) << i);
        A.col[b] = c;
    }
    return A;
}
static GFm gf_inv(const GFm& A) {
    u16 M[14], I[14];
    rows_from(A, M);
    for (int i = 0; i < 14; ++i) I[i] = (u16)(1u << i);
    for (int c = 0; c < 14; ++c) {
        int p = c;
        while (p < 14 && !((M[p] >> c) & 1)) ++p;
        if (p == 14) continue;
        u16 t = M[c]; M[c] = M[p]; M[p] = t;
        t = I[c]; I[c] = I[p]; I[p] = t;
        for (int r2 = 0; r2 < 14; ++r2)
            if (r2 != c && ((M[r2] >> c) & 1)) { M[r2] ^= M[c]; I[r2] ^= I[c]; }
    }
    return from_rows(I);
}

static void build_plan(Plan& pl, u16 rawMm[NPASS][4], u16 rawMt[NPASS][3], u16 rawMw[NPASS][3]) {
    GFm ring, ringInv;
    for (int b = 0; b < 14; ++b) ring.col[b] = (u16)ringp_host(1u << b);
    ringInv = gf_inv(ring);

    GFm phi;
    for (int j = 0; j < 4; ++j) phi.col[10 + j] = (u16)(1u << j);
    for (int j = 0; j < 4; ++j) phi.col[6 + j]  = (u16)(1u << (4 + j));
    for (int j = 0; j < 4; ++j) phi.col[2 + j]  = (u16)(1u << (8 + j));
    phi.col[0] = (u16)(1u << 12);
    phi.col[1] = (u16)(1u << 13);

    for (int b = 0; b < 14; ++b) pl.initM[b] = gf_apply(phi, ring.col[b]);

    const int gb[4][4] = {{10,11,12,13},{6,7,8,9},{2,3,4,5},{0,1,6,7}};

    for (int p = 0; p < NPASS; ++p) {
        const int g = p & 3;
        u16 uv[4];
        if (g < 3) for (int j = 0; j < 4; ++j) uv[j] = (u16)(1u << gb[g + 1][j]);
        else       for (int j = 0; j < 4; ++j) uv[j] = ringInv.col[10 + j];
        for (int j = 0; j < 4; ++j) rawMm[p][j] = gf_apply(phi, uv[j]);

        u16 span[14]; int ns = 0;
        u16 tv[6]; int nt = 0;
        auto tryAdd = [&](u16 v) -> bool {
            bool ch = true;
            while (ch) {
                ch = false;
                for (int i = 0; i < ns; ++i) {
                    const int tb = 31 - __builtin_clz((unsigned)span[i]);
                    if ((v >> tb) & 1) { v ^= span[i]; ch = true; }
                }
            }
            if (!v) return false;
            span[ns++] = v;
            return true;
        };
        for (int j = 0; j < 4; ++j) tryAdd((u16)(1u << gb[g][j]));
        for (int j = 0; j < 4; ++j) tryAdd(uv[j]);
        for (int b2 = 0; b2 < 14 && nt < 6; ++b2)
            if (tryAdd((u16)(1u << b2))) tv[nt++] = (u16)(1u << b2);
        for (int i = 0; i < 3; ++i) rawMt[p][i] = gf_apply(phi, tv[i]);      // tile
        for (int i = 0; i < 3; ++i) rawMw[p][i] = gf_apply(phi, tv[i + 3]);  // wave

        GFm Bm;
        for (int j = 0; j < 4; ++j) Bm.col[j]     = (u16)(1u << gb[g][j]);
        for (int j = 0; j < 4; ++j) Bm.col[4 + j] = uv[j];
        for (int i = 0; i < 6; ++i) Bm.col[8 + i] = tv[i];
        GFm Binv = gf_inv(Bm);
        u16 img[14];
        for (int j = 0; j < 4; ++j) img[j]     = rawMm[p][j];
        for (int j = 0; j < 4; ++j) img[4 + j] = (u16)(1u << j);
        for (int i = 0; i < 6; ++i) img[8 + i] = gf_apply(phi, tv[i]);
        GFm nphi;
        for (int b2 = 0; b2 < 14; ++b2) {
            const u16 coef = gf_apply(Binv, (u16)(1u << b2));
            u16 v = 0;
            for (int j = 0; j < 14; ++j) if ((coef >> j) & 1) v ^= img[j];
            nphi.col[b2] = v;
        }
        if (g == 3) nphi = gf_compose(nphi, ringInv);
        phi = nphi;
    }

    GFm pinv = gf_inv(phi);
    u16 rows[14];
    rows_from(pinv, rows);
    pl.measR = rows[13];
    pl._pad = 0;
}

// ---- per-boundary bank-normalizing involutions psi_p:
// psi(v) = v ^ (par(v&A)<<4) ^ (par(v&B)<<5), A,B subset bits [13:6].
// Chosen so the m->bits[5:4] map (rows psi(Mm[j])) has rank 2 for the pass
// reading at this boundary AND the pass writing into it. ----
static inline int par16(unsigned v) { return __builtin_parity(v); }
static u16 psi_ap(u16 v, unsigned A, unsigned B) {
    return (u16)(v ^ (par16(v & A) << 4) ^ (par16(v & B) << 5));
}
static u16 psi_T(u16 r, unsigned A, unsigned B) {   // transpose, for parity masks
    u16 o = r;
    if ((r >> 4) & 1) o ^= (u16)A;
    if ((r >> 5) & 1) o ^= (u16)B;
    return o;
}
static bool rank2ok(const u16* v, unsigned A, unsigned B) {
    int seen = 0;
    for (int j = 0; j < 4; ++j) {
        const int b4 = ((v[j] >> 4) & 1) ^ par16(v[j] & A);
        const int b5 = ((v[j] >> 5) & 1) ^ par16(v[j] & B);
        const int val = b4 | (b5 << 1);
        if (val) seen |= 1 << val;
    }
    const int cnt = ((seen >> 1) & 1) + ((seen >> 2) & 1) + ((seen >> 3) & 1);
    return cnt >= 2;   // two distinct nonzero values in {01,10,11} are independent
}

static void finalize_plan(Plan& pl, u16 rawMm[NPASS][4], u16 rawMt[NPASS][3],
                          u16 rawMw[NPASS][3]) {
    unsigned psiA[NPASS + 1], psiB[NPASS + 1];
    for (int bd = 0; bd <= NPASS; ++bd) {
        unsigned bestA = 0, bestB = 0;
        bool found = false;
        for (unsigned a = 0; a < 256 && !found; ++a) {
            for (unsigned b = 0; b < 256; ++b) {
                const unsigned A = a << 6, B = b << 6;
                const bool okR = (bd == NPASS) || rank2ok(rawMm[bd], A, B);
                const bool okW = (bd == 0)     || rank2ok(rawMm[bd - 1], A, B);
                if (okR && okW) { bestA = A; bestB = B; found = true; break; }
            }
        }
        psiA[bd] = bestA; psiB[bd] = bestB;
    }
    for (int p = 0; p < NPASS; ++p) {
        for (int j = 0; j < 4; ++j) pl.ps[p].Mm[j] = psi_ap(rawMm[p][j], psiA[p], psiB[p]);
        for (int j = 0; j < 3; ++j) pl.ps[p].Mt[j] = psi_ap(rawMt[p][j], psiA[p], psiB[p]);
        for (int j = 0; j < 3; ++j) pl.ps[p].Mw[j] = psi_ap(rawMw[p][j], psiA[p], psiB[p]);
        for (int j = 0; j < 4; ++j) pl.ps[p].Nm[j] = psi_ap(rawMm[p][j], psiA[p+1], psiB[p+1]);
        for (int j = 0; j < 3; ++j) pl.ps[p].Nt[j] = psi_ap(rawMt[p][j], psiA[p+1], psiB[p+1]);
        for (int j = 0; j < 3; ++j) pl.ps[p].Nw[j] = psi_ap(rawMw[p][j], psiA[p+1], psiB[p+1]);
    }
    for (int b = 0; b < 14; ++b) pl.initM[b] = psi_ap(pl.initM[b], psiA[0], psiB[0]);
    pl.measR = psi_T(pl.measR, psiA[NPASS], psiB[NPASS]);
}

extern "C" void kernel_launch(void* const* d_in, const int* in_sizes, int n_in,
                              void* d_out, int out_size, void* d_ws, size_t ws_size,
                              hipStream_t stream) {
    const float* x_raw  = (const float*)d_in[0];
    const float* angles = (const float*)d_in[1];
    float* out = (float*)d_out;
    const int bsz = in_sizes[0] / NW;

    Plan pl;
    u16 rawMm[NPASS][4], rawMt[NPASS][3], rawMw[NPASS][3];
    build_plan(pl, rawMm, rawMt, rawMw);
    finalize_plan(pl, rawMm, rawMt, rawMw);

    // d_ws layout: [0,12288) W tables (f16), [12288,12736) layer-0 static gates
    f16*    wt_g = (f16*)d_ws;
    float2* u0_g = (float2*)((char*)d_ws + (size_t)NPASS * WTP * sizeof(f16));

    vqc_pre<<<dim3(1), dim3(PRETHR), 0, stream>>>(angles, wt_g, u0_g);

    // 64K state + 12K W tables + 240B G0col/red ~= 78.1 KB -> 2 blocks/CU
    const size_t lds = (size_t)2 * NST * sizeof(f16)
                     + (size_t)NPASS * WTP * sizeof(f16)
                     + (size_t)(2 * NW) * sizeof(float2)
                     + (size_t)(THREADS / 64) * sizeof(float);
    (void)hipFuncSetAttribute((const void*)vqc_kernel,
                              hipFuncAttributeMaxDynamicSharedMemorySize, (int)lds);
    vqc_kernel<<<dim3(bsz), dim3(THREADS), lds, stream>>>(x_raw, wt_g, u0_g, out, pl);
}

// Round 11
// 115.372 us; speedup vs baseline: 1.2631x; 1.2631x over previous
//
#include <hip/hip_runtime.h>
#include <cmath>
#include <cstdint>

#define NW       14
#define NST      (1 << NW)      // 16384 amplitudes
#define THREADS  512
#define PRETHR   768
#define NPASS    12             // layers 1..3 x 4 groups
#define WTP      512            // per-pass W table: TR[256] + TI[256] f16

typedef _Float16 f16;
typedef _Float16 f16x8 __attribute__((ext_vector_type(8)));
typedef float    f32x4 __attribute__((ext_vector_type(4)));
typedef unsigned short u16;

// Per-pass XOR-mask addressing with decoupled read/write frames.
// Base layout = swzu(phi_p(x)) (round-9 proven); each boundary additionally
// gets psi_p: bits {3,4,5} ^= parities of bits [13:6], chosen host-side so
// 8-lane b128 read chunks (Mm[0..2] -> bits[5:3] rank 3) and 16-lane b64
// write chunks (Nm[0..3] -> bits[5:3] rank 3) hit the LDS bank floor.
struct PassArg { u16 Mm[4]; u16 Mt[3]; u16 Mw[3]; u16 Nm[4]; u16 Nt[3]; u16 Nw[3]; };
struct Plan { PassArg ps[NPASS]; u16 initM[14]; u16 measR; u16 _pad; };

__device__ __forceinline__ float2 cmulf(float2 a, float2 b) {
    return make_float2(a.x * b.x - a.y * b.y, a.x * b.y + a.y * b.x);
}
// W-table in-block offset with quad-spread (keeps 8-f16 alignment)
__device__ __host__ __forceinline__ unsigned wtofs(unsigned m, unsigned q01) {
    return (m * 16 + q01 * 8) ^ (((m >> 2) & 1u) << 3);
}

// ---------------- pre-kernel: shared tables (angles only) -> d_ws ----------------
__global__ __launch_bounds__(PRETHR)
void vqc_pre(const float* __restrict__ angles, f16* __restrict__ wt_g,
             float2* __restrict__ u0_g)
{
    __shared__ float2 G[4 * NW * 4];
    const int tid = threadIdx.x;

    if (tid < 4 * NW) {
        const int k = tid / NW, w = tid % NW;
        const float a  = angles[(k * NW + w) * 3 + 0];
        const float bb = angles[(k * NW + w) * 3 + 1];
        const float c  = angles[(k * NW + w) * 3 + 2];
        float sa, ca, sb, cb, sc, cc;
        sincosf(a * 0.5f, &sa, &ca);
        sincosf(bb * 0.5f, &sb, &cb);
        sincosf(c * 0.5f, &sc, &cc);
        float2 m00 = make_float2(cb * ca,  sb * sa);
        float2 m01 = make_float2(-sb * ca, -cb * sa);
        float2 m10 = make_float2(sb * ca,  -cb * sa);
        float2 m11 = make_float2(cb * ca,  -sb * sa);
        const float2 e0 = make_float2(cc, -sc), e1 = make_float2(cc, sc);
        const float2 u00 = cmulf(e0, m00), u01 = cmulf(e0, m01);
        const float2 u10 = cmulf(e1, m10), u11 = cmulf(e1, m11);
        const int gi = (k * NW + w) * 4;
        G[gi + 0] = u00; G[gi + 1] = u01; G[gi + 2] = u10; G[gi + 3] = u11;
        if (k == 0) {   // layer-0 STATIC gate (per-sample RY_enc folded in main kernel)
            u0_g[w * 4 + 0] = u00; u0_g[w * 4 + 1] = u01;
            u0_g[w * 4 + 2] = u10; u0_g[w * 4 + 3] = u11;
        }
    }
    __syncthreads();

    // W tables: TR[a'][a] = Re W[a'][a], TI = Im (16x16 per pass), layers 1..3
    {
        const int p = tid >> 6, l6 = tid & 63;
        const int ap = l6 & 15, ahalf = (l6 >> 4) & 1, dup = l6 >> 5;
        const int layer = (p >> 2) + 1, g = p & 3;

        float2 p3;
        if (g == 3) {
            p3 = make_float2((((ap >> 3) & 1) == ahalf) ? 1.f : 0.f, 0.f);
        } else {
            const int wire = 13 - (10 - 4 * g + 3);
            p3 = G[(layer * NW + wire) * 4 + ((ap >> 3) & 1) * 2 + ahalf];
        }
        float2 e0a, e0b, e1a, e1b, e2a, e2b;
        {
            const int r0 = ap & 1, r1 = (ap >> 1) & 1, r2 = (ap >> 2) & 1;
            if (g == 3) {
                const float2* G13 = G + (layer * NW + 13) * 4;
                const float2* G12 = G + (layer * NW + 12) * 4;
                e0a = G13[r0 * 2 + 0]; e0b = G13[r0 * 2 + 1];
                e1a = G12[r1 * 2 + 0]; e1b = G12[r1 * 2 + 1];
                e2a = make_float2(r2 == 0 ? 1.f : 0.f, 0.f);
                e2b = make_float2(r2 == 1 ? 1.f : 0.f, 0.f);
            } else {
                const float2* G0 = G + (layer * NW + (13 - (10 - 4 * g + 0))) * 4;
                const float2* G1 = G + (layer * NW + (13 - (10 - 4 * g + 1))) * 4;
                const float2* G2 = G + (layer * NW + (13 - (10 - 4 * g + 2))) * 4;
                e0a = G0[r0 * 2 + 0]; e0b = G0[r0 * 2 + 1];
                e1a = G1[r1 * 2 + 0]; e1b = G1[r1 * 2 + 1];
                e2a = G2[r2 * 2 + 0]; e2b = G2[r2 * 2 + 1];
            }
        }
        f16x8 frag;
        #pragma unroll
        for (int j2 = 0; j2 < 8; ++j2) {
            float2 v = cmulf(p3, (j2 & 4) ? e2b : e2a);
            v = cmulf(v, (j2 & 2) ? e1b : e1a);
            v = cmulf(v, (j2 & 1) ? e0b : e0a);
            frag[j2] = (f16)(dup ? v.y : v.x);
        }
        *(f16x8*)(wt_g + p * WTP + dup * 256 + wtofs(ap, ahalf)) = frag;
    }
}

// ---------------- main kernel: per-sample ----------------
__global__ __launch_bounds__(THREADS, 4)
void vqc_kernel(const float* __restrict__ x_raw, const f16* __restrict__ wt_g,
                const float2* __restrict__ u0_g, float* __restrict__ out, Plan pl)
{
    extern __shared__ char smem[];
    f16*    Sh  = (f16*)smem;                    // Re [0,16K), Im [16K,32K) f16 (64 KB)
    f16*    Wt  = Sh + 2 * NST;                  // 12 KB shared W tables
    float2* G0c = (float2*)(Wt + NPASS * WTP);   // 14 x {col0_row0, col0_row1}
    float*  red = (float*)(G0c + 2 * NW);

    const int b   = blockIdx.x;
    const int tid = threadIdx.x;
    const int lane = tid & 63, wv = tid >> 6;
    const int q = lane >> 4, m = lane & 15;

    // ---- stage shared W tables: global -> LDS (768 x 16 B, coalesced) ----
    {
        const uint4* src = (const uint4*)wt_g;
        uint4* dst = (uint4*)Wt;
        dst[tid] = src[tid];
        if (tid < 256) dst[512 + tid] = src[512 + tid];
    }
    // ---- per-sample layer-0 encode: col0 of U_static * RY_enc(x_w) ----
    if (tid < NW) {
        const float xe = tanhf(x_raw[b * NW + tid]) * 3.14159265358979f;
        float se, ce;
        sincosf(xe * 0.5f, &se, &ce);
        const float2 u00 = u0_g[tid * 4 + 0], u01 = u0_g[tid * 4 + 1];
        const float2 u10 = u0_g[tid * 4 + 2], u11 = u0_g[tid * 4 + 3];
        G0c[tid * 2 + 0] = make_float2(u00.x * ce + u01.x * se, u00.y * ce + u01.y * se);
        G0c[tid * 2 + 1] = make_float2(u10.x * ce + u11.x * se, u10.y * ce + u11.y * se);
    }
    __syncthreads();

    // ---- init: product state after all layer-0 1q gates, placed via initM ----
    {
        float2 common = make_float2(1.f, 0.f);
        #pragma unroll
        for (int bit = 0; bit < 9; ++bit) {          // x bits 0..8 from tid (wires 13..5)
            const int w = 13 - bit;
            const float2 f = ((tid >> bit) & 1) ? G0c[w * 2 + 1] : G0c[w * 2 + 0];
            common = cmulf(common, f);
        }
        unsigned p9 = 0;
        #pragma unroll
        for (int bit = 0; bit < 9; ++bit)
            p9 ^= ((tid >> bit) & 1) ? (unsigned)pl.initM[bit] : 0u;
        float2 f0[2], f1[2], f2[2], f3[2], f4[2];    // j bits 0..4 -> wires 4,3,2,1,0
        f0[0] = G0c[4*2+0]; f0[1] = G0c[4*2+1];
        f1[0] = G0c[3*2+0]; f1[1] = G0c[3*2+1];
        f2[0] = G0c[2*2+0]; f2[1] = G0c[2*2+1];
        f3[0] = G0c[1*2+0]; f3[1] = G0c[1*2+1];
        f4[0] = G0c[0*2+0]; f4[1] = G0c[0*2+1];
        #pragma unroll
        for (int j = 0; j < 32; ++j) {
            float2 o = cmulf(cmulf(f0[j & 1], f1[(j >> 1) & 1]),
                             cmulf(f2[(j >> 2) & 1], f3[(j >> 3) & 1]));
            o = cmulf(o, f4[(j >> 4) & 1]);
            const float2 amp = cmulf(common, o);
            const unsigned ph = p9
                ^ ((j & 1) ? pl.initM[9]  : 0) ^ ((j & 2)  ? pl.initM[10] : 0)
                ^ ((j & 4) ? pl.initM[11] : 0) ^ ((j & 8)  ? pl.initM[12] : 0)
                ^ ((j & 16) ? pl.initM[13] : 0);
            Sh[ph]       = (f16)amp.x;
            Sh[ph + NST] = (f16)amp.y;
        }
    }
    __syncthreads();

    // ---- 12 MFMA passes, in-place: read 8 tiles -> barrier -> MFMA+write -> barrier ----
    const unsigned plane_off = (unsigned)(q >> 1) << 14;
    const unsigned q01 = (unsigned)(q & 1);
    const f32x4 z4 = {0.f, 0.f, 0.f, 0.f};
    #pragma unroll
    for (int p = 0; p < NPASS; ++p) {
        const PassArg& P = pl.ps[p];
        const unsigned b0R = ((m & 1) ? P.Mm[0] : 0) ^ ((m & 2) ? P.Mm[1] : 0)
                           ^ ((m & 4) ? P.Mm[2] : 0) ^ ((m & 8) ? P.Mm[3] : 0)
                           ^ ((wv & 1) ? P.Mw[0] : 0) ^ ((wv & 2) ? P.Mw[1] : 0)
                           ^ ((wv & 4) ? P.Mw[2] : 0);
        const unsigned b0W = ((m & 1) ? P.Nm[0] : 0) ^ ((m & 2) ? P.Nm[1] : 0)
                           ^ ((m & 4) ? P.Nm[2] : 0) ^ ((m & 8) ? P.Nm[3] : 0)
                           ^ ((wv & 1) ? P.Nw[0] : 0) ^ ((wv & 2) ? P.Nw[1] : 0)
                           ^ ((wv & 4) ? P.Nw[2] : 0);
        const f16x8 tr = *(const f16x8*)(Wt + p * WTP +       wtofs((unsigned)m, q01));
        const f16x8 ti = *(const f16x8*)(Wt + p * WTP + 256 + wtofs((unsigned)m, q01));
        const f16x8 bf1 = (q < 2) ? tr : -ti;   // [Wr' ; -Wi']
        const f16x8 bf2 = (q < 2) ? ti : tr;    // [Wi' ;  Wr']
        f16x8 av[8];
        #pragma unroll
        for (int tt = 0; tt < 8; ++tt) {
            const unsigned swR = b0R ^ ((tt & 1) ? P.Mt[0] : 0)
                                     ^ ((tt & 2) ? P.Mt[1] : 0)
                                     ^ ((tt & 4) ? P.Mt[2] : 0);
            av[tt] = *(const f16x8*)(Sh + plane_off + (swR ^ (q01 << 3)));
        }
        __syncthreads();    // all reads complete before any in-place write
        #pragma unroll
        for (int tt = 0; tt < 8; ++tt) {
            const f32x4 d1 = __builtin_amdgcn_mfma_f32_16x16x32_f16(av[tt], bf1, z4, 0, 0, 0);
            const f32x4 d2 = __builtin_amdgcn_mfma_f32_16x16x32_f16(av[tt], bf2, z4, 0, 0, 0);
            union { f16 h[4]; uint2 u; } c1, c2;
            #pragma unroll
            for (int r = 0; r < 4; ++r) { c1.h[r] = (f16)d1[r]; c2.h[r] = (f16)d2[r]; }
            const unsigned wu = (b0W ^ ((tt & 1) ? P.Nt[0] : 0)
                                     ^ ((tt & 2) ? P.Nt[1] : 0)
                                     ^ ((tt & 4) ? P.Nt[2] : 0)) ^ ((unsigned)q << 2);
            *(uint2*)(Sh + wu)       = c1.u;   // Re plane, b64
            *(uint2*)(Sh + NST + wu) = c2.u;   // Im plane, b64
        }
        __syncthreads();
    }

    // ---- <Z_0>: sign = parity(s & measR); lane-interleaved chunks for bank spread ----
    float acc = 0.f;
    {
        const unsigned base = (unsigned)tid * 32;
        const int pb = __popc(base & (unsigned)pl.measR) & 1;
        #pragma unroll
        for (int cch = 0; cch < 4; ++cch) {
            const unsigned co = ((unsigned)cch ^ ((unsigned)(lane >> 1) & 3u)) * 8;
            const f16x8 rr = *(const f16x8*)(Sh + (base ^ co));
            const f16x8 ii = *(const f16x8*)(Sh + NST + (base ^ co));
            #pragma unroll
            for (int e = 0; e < 8; ++e) {
                const float re = (float)rr[e], im = (float)ii[e];
                const float pw = fmaf(re, re, im * im);
                const int sgn = pb ^ (__popc((co | (unsigned)e) & (unsigned)pl.measR) & 1);
                acc += sgn ? -pw : pw;
            }
        }
    }
    #pragma unroll
    for (int off = 32; off > 0; off >>= 1) acc += __shfl_down(acc, off);
    if ((tid & 63) == 0) red[wv] = acc;
    __syncthreads();
    if (tid == 0) {
        float s = 0.f;
        #pragma unroll
        for (int i = 0; i < THREADS / 64; ++i) s += red[i];
        out[b] = s;
    }
}

// ---------------- host-side GF(2) layout scheduling ----------------
struct GFm { u16 col[14]; };   // col[b] = image of e_b

static unsigned ringp_host(unsigned x) {
    unsigned s = x;
    s ^= s >> 1; s ^= s >> 2; s ^= s >> 4; s ^= s >> 8;
    s &= 0x3FFFu;
    return (s ^ ((s & 1u) << 13)) & 0x3FFFu;
}
static u16 gf_apply(const GFm& m, u16 v) {
    u16 r = 0;
    for (int b = 0; b < 14; ++b) if ((v >> b) & 1) r ^= m.col[b];
    return r;
}
static GFm gf_compose(const GFm& A, const GFm& B) {
    GFm C;
    for (int b = 0; b < 14; ++b) C.col[b] = gf_apply(A, B.col[b]);
    return C;
}
static void rows_from(const GFm& A, u16 r[14]) {
    for (int i = 0; i < 14; ++i) {
        u16 mm = 0;
        for (int b = 0; b < 14; ++b) mm |= (u16)(((A.col[b] >> i) & 1) << b);
        r[i] = mm;
    }
}
static GFm from_rows(const u16 r[14]) {
    GFm A;
    for (int b = 0; b < 14; ++b) {
        u16 c = 0;
        for (int i = 0; i < 14; ++i) c |= (u16)(((r[i] >> b) & 1) << i);
        A.col[b] = c;
    }
    return A;
}
static GFm gf_inv(const GFm& A) {
    u16 M[14], I[14];
    rows_from(A, M);
    for (int i = 0; i < 14; ++i) I[i] = (u16)(1u << i);
    for (int c = 0; c < 14; ++c) {
        int p = c;
        while (p < 14 && !((M[p] >> c) & 1)) ++p;
        if (p == 14) continue;
        u16 t = M[c]; M[c] = M[p]; M[p] = t;
        t = I[c]; I[c] = I[p]; I[p] = t;
        for (int r2 = 0; r2 < 14; ++r2)
            if (r2 != c && ((M[r2] >> c) & 1)) { M[r2] ^= M[c]; I[r2] ^= I[c]; }
    }
    return from_rows(I);
}

static void build_plan(Plan& pl, u16 rawMm[NPASS][4], u16 rawMt[NPASS][3], u16 rawMw[NPASS][3]) {
    GFm ring, ringInv;
    for (int b = 0; b < 14; ++b) ring.col[b] = (u16)ringp_host(1u << b);
    ringInv = gf_inv(ring);

    GFm phi;
    for (int j = 0; j < 4; ++j) phi.col[10 + j] = (u16)(1u << j);
    for (int j = 0; j < 4; ++j) phi.col[6 + j]  = (u16)(1u << (4 + j));
    for (int j = 0; j < 4; ++j) phi.col[2 + j]  = (u16)(1u << (8 + j));
    phi.col[0] = (u16)(1u << 12);
    phi.col[1] = (u16)(1u << 13);

    for (int b = 0; b < 14; ++b) pl.initM[b] = gf_apply(phi, ring.col[b]);

    const int gb[4][4] = {{10,11,12,13},{6,7,8,9},{2,3,4,5},{0,1,6,7}};

    for (int p = 0; p < NPASS; ++p) {
        const int g = p & 3;
        u16 uv[4];
        if (g < 3) for (int j = 0; j < 4; ++j) uv[j] = (u16)(1u << gb[g + 1][j]);
        else       for (int j = 0; j < 4; ++j) uv[j] = ringInv.col[10 + j];
        for (int j = 0; j < 4; ++j) rawMm[p][j] = gf_apply(phi, uv[j]);

        u16 span[14]; int ns = 0;
        u16 tv[6]; int nt = 0;
        auto tryAdd = [&](u16 v) -> bool {
            bool ch = true;
            while (ch) {
                ch = false;
                for (int i = 0; i < ns; ++i) {
                    const int tb = 31 - __builtin_clz((unsigned)span[i]);
                    if ((v >> tb) & 1) { v ^= span[i]; ch = true; }
                }
            }
            if (!v) return false;
            span[ns++] = v;
            return true;
        };
        for (int j = 0; j < 4; ++j) tryAdd((u16)(1u << gb[g][j]));
        for (int j = 0; j < 4; ++j) tryAdd(uv[j]);
        for (int b2 = 0; b2 < 14 && nt < 6; ++b2)
            if (tryAdd((u16)(1u << b2))) tv[nt++] = (u16)(1u << b2);
        for (int i = 0; i < 3; ++i) rawMt[p][i] = gf_apply(phi, tv[i]);      // tile
        for (int i = 0; i < 3; ++i) rawMw[p][i] = gf_apply(phi, tv[i + 3]);  // wave

        GFm Bm;
        for (int j = 0; j < 4; ++j) Bm.col[j]     = (u16)(1u << gb[g][j]);
        for (int j = 0; j < 4; ++j) Bm.col[4 + j] = uv[j];
        for (int i = 0; i < 6; ++i) Bm.col[8 + i] = tv[i];
        GFm Binv = gf_inv(Bm);
        u16 img[14];
        for (int j = 0; j < 4; ++j) img[j]     = rawMm[p][j];
        for (int j = 0; j < 4; ++j) img[4 + j] = (u16)(1u << j);
        for (int i = 0; i < 6; ++i) img[8 + i] = gf_apply(phi, tv[i]);
        GFm nphi;
        for (int b2 = 0; b2 < 14; ++b2) {
            const u16 coef = gf_apply(Binv, (u16)(1u << b2));
            u16 v = 0;
            for (int j = 0; j < 14; ++j) if ((coef >> j) & 1) v ^= img[j];
            nphi.col[b2] = v;
        }
        if (g == 3) nphi = gf_compose(nphi, ringInv);
        phi = nphi;
    }

    GFm pinv = gf_inv(phi);
    u16 rows[14];
    rows_from(pinv, rows);
    pl.measR = rows[13];
    pl._pad = 0;
}

// ---- round-9 base hash (proven): bits [5:3] ^= parities of high bits ----
static inline int par16(unsigned v) { return __builtin_parity(v); }
static u16 swz_h(u16 v) {
    return (u16)(v ^ ((((v >> 6) ^ (v >> 9) ^ (v >> 11)) & 7u) << 3));
}
static u16 swzT_h(u16 r) {
    u16 o = r;
    if ((r >> 3) & 1) o ^= (u16)((1u << 6) | (1u << 9)  | (1u << 11));
    if ((r >> 4) & 1) o ^= (u16)((1u << 7) | (1u << 10) | (1u << 12));
    if ((r >> 5) & 1) o ^= (u16)((1u << 8) | (1u << 11) | (1u << 13));
    return o;
}
// ---- per-boundary psi: bits {3,4,5} ^= par(v&A/B/C), A,B,C subset [13:6] ----
static u16 psi3(u16 v, unsigned A, unsigned B, unsigned C) {
    return (u16)(v ^ (par16(v & A) << 3) ^ (par16(v & B) << 4) ^ (par16(v & C) << 5));
}
static u16 psi3T(u16 r, unsigned A, unsigned B, unsigned C) {
    u16 o = r;
    if ((r >> 3) & 1) o ^= (u16)A;
    if ((r >> 4) & 1) o ^= (u16)B;
    if ((r >> 5) & 1) o ^= (u16)C;
    return o;
}
// rank over GF(2) of {bits [5:3] of psi3(v_i)} (3-bit vectors)
static int rank53(const u16* v, int n, unsigned A, unsigned B, unsigned C) {
    unsigned basis[3] = {0, 0, 0};
    int rank = 0;
    for (int i = 0; i < n; ++i) {
        unsigned x = (((unsigned)(v[i] >> 3) & 1u) ^ (unsigned)par16(v[i] & A))
                   | (((((unsigned)(v[i] >> 4) & 1u) ^ (unsigned)par16(v[i] & B))) << 1)
                   | (((((unsigned)(v[i] >> 5) & 1u) ^ (unsigned)par16(v[i] & C))) << 2);
        for (int bb = 2; bb >= 0; --bb) {
            if ((x >> bb) & 1) {
                if (basis[bb]) x ^= basis[bb];
                else { basis[bb] = x; ++rank; break; }
            }
        }
    }
    return rank;
}

static void finalize_plan(Plan& pl, u16 rawMm[NPASS][4], u16 rawMt[NPASS][3],
                          u16 rawMw[NPASS][3]) {
    // step 1: swzu base (round-9 proven layout)
    u16 sMm[NPASS][4], sMt[NPASS][3], sMw[NPASS][3];
    for (int p = 0; p < NPASS; ++p) {
        for (int j = 0; j < 4; ++j) sMm[p][j] = swz_h(rawMm[p][j]);
        for (int j = 0; j < 3; ++j) sMt[p][j] = swz_h(rawMt[p][j]);
        for (int j = 0; j < 3; ++j) sMw[p][j] = swz_h(rawMw[p][j]);
    }
    u16 sInit[14];
    for (int b = 0; b < 14; ++b) sInit[b] = swz_h(pl.initM[b]);
    u16 sMeas = swzT_h(pl.measR);

    // step 2: per-boundary psi3 search (psi=0 falls back to round-9 exactly)
    unsigned pA[NPASS + 1], pB[NPASS + 1], pC[NPASS + 1];
    for (int bd = 0; bd <= NPASS; ++bd) {
        const bool hasR = (bd < NPASS), hasW = (bd > 0);
        auto score = [&](unsigned A, unsigned B, unsigned C) -> int {
            const int rR = hasR ? rank53(sMm[bd], 3, A, B, C) : 3;       // 8-lane read chunks
            const int rW = hasW ? rank53(sMm[bd - 1], 4, A, B, C) : 3;   // 16-lane write chunks
            return rR + rW;
        };
        unsigned bA = 0, bB = 0, bC = 0;
        int bScore = score(0, 0, 0);
        unsigned seed = 0x9E3779B9u + (unsigned)bd * 0x85EBCA6Bu;
        for (int it = 0; it < 60000 && bScore < 6; ++it) {
            seed = seed * 1664525u + 1013904223u;
            const unsigned A = ((seed >> 8)  & 0xFFu) << 6;
            const unsigned B = ((seed >> 16) & 0xFFu) << 6;
            const unsigned C = ((seed >> 24) & 0xFFu) << 6;
            const int sc = score(A, B, C);
            if (sc > bScore) { bScore = sc; bA = A; bB = B; bC = C; }
        }
        pA[bd] = bA; pB[bd] = bB; pC[bd] = bC;
    }

    // step 3: fold
    for (int p = 0; p < NPASS; ++p) {
        for (int j = 0; j < 4; ++j) pl.ps[p].Mm[j] = psi3(sMm[p][j], pA[p], pB[p], pC[p]);
        for (int j = 0; j < 3; ++j) pl.ps[p].Mt[j] = psi3(sMt[p][j], pA[p], pB[p], pC[p]);
        for (int j = 0; j < 3; ++j) pl.ps[p].Mw[j] = psi3(sMw[p][j], pA[p], pB[p], pC[p]);
        for (int j = 0; j < 4; ++j) pl.ps[p].Nm[j] = psi3(sMm[p][j], pA[p+1], pB[p+1], pC[p+1]);
        for (int j = 0; j < 3; ++j) pl.ps[p].Nt[j] = psi3(sMt[p][j], pA[p+1], pB[p+1], pC[p+1]);
        for (int j = 0; j < 3; ++j) pl.ps[p].Nw[j] = psi3(sMw[p][j], pA[p+1], pB[p+1], pC[p+1]);
    }
    for (int b = 0; b < 14; ++b) pl.initM[b] = psi3(sInit[b], pA[0], pB[0], pC[0]);
    pl.measR = psi3T(sMeas, pA[NPASS], pB[NPASS], pC[NPASS]);
}

extern "C" void kernel_launch(void* const* d_in, const int* in_sizes, int n_in,
                              void* d_out, int out_size, void* d_ws, size_t ws_size,
                              hipStream_t stream) {
    const float* x_raw  = (const float*)d_in[0];
    const float* angles = (const float*)d_in[1];
    float* out = (float*)d_out;
    const int bsz = in_sizes[0] / NW;

    Plan pl;
    u16 rawMm[NPASS][4], rawMt[NPASS][3], rawMw[NPASS][3];
    build_plan(pl, rawMm, rawMt, rawMw);
    finalize_plan(pl, rawMm, rawMt, rawMw);

    // d_ws layout: [0,12288) W tables (f16), [12288,12736) layer-0 static gates
    f16*    wt_g = (f16*)d_ws;
    float2* u0_g = (float2*)((char*)d_ws + (size_t)NPASS * WTP * sizeof(f16));

    vqc_pre<<<dim3(1), dim3(PRETHR), 0, stream>>>(angles, wt_g, u0_g);

    // 64K state + 12K W tables + 240B G0col/red ~= 78.1 KB -> 2 blocks/CU
    const size_t lds = (size_t)2 * NST * sizeof(f16)
                     + (size_t)NPASS * WTP * sizeof(f16)
                     + (size_t)(2 * NW) * sizeof(float2)
                     + (size_t)(THREADS / 64) * sizeof(float);
    (void)hipFuncSetAttribute((const void*)vqc_kernel,
                              hipFuncAttributeMaxDynamicSharedMemorySize, (int)lds);
    vqc_kernel<<<dim3(bsz), dim3(THREADS), lds, stream>>>(x_raw, wt_g, u0_g, out, pl);
}